// Round 1
// baseline (4450.365 us; speedup 1.0000x reference)
//
#include <hip/hip_runtime.h>

// GCN: 3x (linear -> gather(src) -> scatter_add(dst) -> bias+act)
// N=100000 nodes, E=1600000 edges, IN=128, HID=OUT=64.

#define FOUT 64

// out[n,64] = in[n,K] @ W[K,64]; W staged in LDS. One wave per row,
// lane = output feature (coalesced W/out access, broadcast x reads).
template<int K>
__global__ __launch_bounds__(256) void k_linear(
    const float* __restrict__ in, const float* __restrict__ W,
    float* __restrict__ out, int n) {
    __shared__ float sW[K * FOUT];
    for (int i = threadIdx.x; i < K * FOUT; i += blockDim.x) sW[i] = W[i];
    __syncthreads();

    const int lane = threadIdx.x & 63;
    const int wid = threadIdx.x >> 6;
    const int wavesPerBlock = blockDim.x >> 6;
    const int stride = gridDim.x * wavesPerBlock;

    for (int row = blockIdx.x * wavesPerBlock + wid; row < n; row += stride) {
        const float* xr = in + (size_t)row * K;
        float acc = 0.f;
#pragma unroll 16
        for (int k = 0; k < K; ++k) {
            acc = fmaf(xr[k], sW[k * FOUT + lane], acc);
        }
        out[(size_t)row * FOUT + lane] = acc;
    }
}

// Scatter-add: 16 threads per edge, each owns a float4 feature quad.
__global__ __launch_bounds__(256) void k_scatter(
    const int* __restrict__ src, const int* __restrict__ dst,
    const float* __restrict__ msg, float* __restrict__ acc, int ne) {
    const int total = ne * 16;
    const int stride = gridDim.x * blockDim.x;
    for (int i = blockIdx.x * blockDim.x + threadIdx.x; i < total; i += stride) {
        const int e = i >> 4;
        const int fq = (i & 15) << 2;
        const int s = src[e];
        const int d = dst[e];
        const float4 v = *reinterpret_cast<const float4*>(msg + (size_t)s * FOUT + fq);
        float* p = acc + (size_t)d * FOUT + fq;
        atomicAdd(p + 0, v.x);
        atomicAdd(p + 1, v.y);
        atomicAdd(p + 2, v.z);
        atomicAdd(p + 3, v.w);
    }
}

// In-place bias + ReLU over n*64 elements.
__global__ __launch_bounds__(256) void k_bias_relu(
    float* __restrict__ h, const float* __restrict__ b, int n64) {
    const int stride = gridDim.x * blockDim.x;
    for (int i = blockIdx.x * blockDim.x + threadIdx.x; i < n64; i += stride) {
        float v = h[i] + b[i & (FOUT - 1)];
        h[i] = v > 0.f ? v : 0.f;
    }
}

// In-place bias + sigmoid over n*64 elements.
__global__ __launch_bounds__(256) void k_bias_sigmoid(
    float* __restrict__ h, const float* __restrict__ b, int n64) {
    const int stride = gridDim.x * blockDim.x;
    for (int i = blockIdx.x * blockDim.x + threadIdx.x; i < n64; i += stride) {
        float v = h[i] + b[i & (FOUT - 1)];
        h[i] = 1.f / (1.f + __expf(-v));
    }
}

extern "C" void kernel_launch(void* const* d_in, const int* in_sizes, int n_in,
                              void* d_out, int out_size, void* d_ws, size_t ws_size,
                              hipStream_t stream) {
    const float* x  = (const float*)d_in[0];
    const int*   ei = (const int*)d_in[1];
    const float* W1 = (const float*)d_in[2];
    const float* b1 = (const float*)d_in[3];
    const float* W2 = (const float*)d_in[4];
    const float* b2 = (const float*)d_in[5];
    const float* W3 = (const float*)d_in[6];
    const float* b3 = (const float*)d_in[7];
    float* out = (float*)d_out;

    const int n  = in_sizes[0] / 128;   // 100000
    const int ne = in_sizes[1] / 2;     // 1600000
    const int* src = ei;
    const int* dst = ei + ne;

    const size_t feat_elems = (size_t)n * FOUT;
    float* A = (float*)d_ws;            // 25.6 MB
    float* B = A + feat_elems;          // 25.6 MB

    const int gGemm = 2048, gScat = 2048, gEw = 2048;

    // ---- Layer 1: A = x@W1; B = scatter(A); B = relu(B+b1) ----
    k_linear<128><<<gGemm, 256, 0, stream>>>(x, W1, A, n);
    hipMemsetAsync(B, 0, feat_elems * sizeof(float), stream);
    k_scatter<<<gScat, 256, 0, stream>>>(src, dst, A, B, ne);
    k_bias_relu<<<gEw, 256, 0, stream>>>(B, b1, n * FOUT);

    // ---- Layer 2: A = B@W2; B' = scatter(A) into B? (need separate) ----
    // GEMM2 reads B writes A; then zero B? B is still the GEMM input...
    // GEMM is complete before scatter runs (stream order), so B is dead
    // after k_linear finishes: safe to reuse as the accumulator.
    k_linear<64><<<gGemm, 256, 0, stream>>>(B, W2, A, n);
    hipMemsetAsync(B, 0, feat_elems * sizeof(float), stream);
    k_scatter<<<gScat, 256, 0, stream>>>(src, dst, A, B, ne);
    k_bias_relu<<<gEw, 256, 0, stream>>>(B, b2, n * FOUT);

    // ---- Layer 3: A = B@W3; out = scatter(A); out = sigmoid(out+b3) ----
    k_linear<64><<<gGemm, 256, 0, stream>>>(B, W3, A, n);
    hipMemsetAsync(out, 0, feat_elems * sizeof(float), stream);
    k_scatter<<<gScat, 256, 0, stream>>>(src, dst, A, out, ne);
    k_bias_sigmoid<<<gEw, 256, 0, stream>>>(out, b3, n * FOUT);
}

// Round 4
// 781.846 us; speedup vs baseline: 5.6921x; 5.6921x over previous
//
#include <hip/hip_runtime.h>

// GCN: 3x (linear -> aggregate_by_dst(CSR) -> bias+act), atomic-free float path.
// N=100000, E=1600000, IN=128, HID=OUT=64.

#define FOUT 64
#define SCAN_T 256
#define SCAN_ELEMS 1024   // elements per scan block (4 per thread)

// ---------------- dense linear ----------------
// out[n,64] = in[n,K] @ W[K,64]; W staged in LDS. One wave per row,
// lane = output feature (coalesced W/out, wave-uniform x reads).
template<int K>
__global__ __launch_bounds__(256) void k_linear(
    const float* __restrict__ in, const float* __restrict__ W,
    float* __restrict__ out, int n) {
    __shared__ float sW[K * FOUT];
    for (int i = threadIdx.x; i < K * FOUT; i += blockDim.x) sW[i] = W[i];
    __syncthreads();

    const int lane = threadIdx.x & 63;
    const int wid = threadIdx.x >> 6;
    const int wavesPerBlock = blockDim.x >> 6;
    const int stride = gridDim.x * wavesPerBlock;

    for (int row = blockIdx.x * wavesPerBlock + wid; row < n; row += stride) {
        const float* xr = in + (size_t)row * K;
        float acc = 0.f;
#pragma unroll 16
        for (int k = 0; k < K; ++k) {
            acc = fmaf(xr[k], sW[k * FOUT + lane], acc);
        }
        out[(size_t)row * FOUT + lane] = acc;
    }
}

// ---------------- CSR build ----------------
__global__ __launch_bounds__(256) void k_hist(
    const int* __restrict__ dst, int* __restrict__ cnt, int ne) {
    const int stride = gridDim.x * blockDim.x;
    for (int i = blockIdx.x * blockDim.x + threadIdx.x; i < ne; i += stride)
        atomicAdd(&cnt[dst[i]], 1);
}

// Per-block exclusive scan of cnt -> row_ofs (block-local), block totals -> partials.
__global__ __launch_bounds__(SCAN_T) void k_scan1(
    const int* __restrict__ cnt, int* __restrict__ ex,
    int* __restrict__ partials, int n) {
    __shared__ int s[SCAN_T];
    const int base = blockIdx.x * SCAN_ELEMS;
    int vals[4];
    int sum = 0;
#pragma unroll
    for (int j = 0; j < 4; ++j) {
        int idx = base + threadIdx.x * 4 + j;
        int v = (idx < n) ? cnt[idx] : 0;
        vals[j] = sum;          // exclusive prefix within thread
        sum += v;
    }
    s[threadIdx.x] = sum;
    __syncthreads();
    // Hillis-Steele inclusive scan of thread totals
    for (int ofs = 1; ofs < SCAN_T; ofs <<= 1) {
        int v = (threadIdx.x >= ofs) ? s[threadIdx.x - ofs] : 0;
        __syncthreads();
        s[threadIdx.x] += v;
        __syncthreads();
    }
    const int texc = s[threadIdx.x] - sum;   // exclusive prefix of this thread
#pragma unroll
    for (int j = 0; j < 4; ++j) {
        int idx = base + threadIdx.x * 4 + j;
        if (idx < n) ex[idx] = texc + vals[j];
    }
    if (threadIdx.x == SCAN_T - 1) partials[blockIdx.x] = s[threadIdx.x];
}

// Exclusive scan of block partials (nb <= 256).
__global__ __launch_bounds__(SCAN_T) void k_scan2(
    const int* __restrict__ partials, int* __restrict__ partial_ofs, int nb) {
    __shared__ int s[SCAN_T];
    int v = (threadIdx.x < nb) ? partials[threadIdx.x] : 0;
    s[threadIdx.x] = v;
    __syncthreads();
    for (int ofs = 1; ofs < SCAN_T; ofs <<= 1) {
        int t = (threadIdx.x >= ofs) ? s[threadIdx.x - ofs] : 0;
        __syncthreads();
        s[threadIdx.x] += t;
        __syncthreads();
    }
    if (threadIdx.x < nb) partial_ofs[threadIdx.x] = s[threadIdx.x] - v;
}

// Add block offsets, finalize row_ofs, and init cursor = row_ofs.
__global__ __launch_bounds__(256) void k_scan3(
    int* __restrict__ row_ofs, const int* __restrict__ partial_ofs,
    int* __restrict__ cursor, int n, int ne) {
    const int i = blockIdx.x * blockDim.x + threadIdx.x;
    if (i < n) {
        int v = row_ofs[i] + partial_ofs[i >> 10];
        row_ofs[i] = v;
        cursor[i] = v;
    }
    if (i == 0) row_ofs[n] = ne;
}

__global__ __launch_bounds__(256) void k_fill(
    const int* __restrict__ src, const int* __restrict__ dst,
    int* __restrict__ cursor, int* __restrict__ csr_src, int ne) {
    const int stride = gridDim.x * blockDim.x;
    for (int i = blockIdx.x * blockDim.x + threadIdx.x; i < ne; i += stride) {
        int d = dst[i];
        int p = atomicAdd(&cursor[d], 1);
        csr_src[p] = src[i];
    }
}

// ---------------- aggregation (gather-reduce) ----------------
// One wave per node; lane = feature. acc = sum over in-edges of msg[src][lane],
// then bias + activation fused. ACT: 0 = ReLU, 1 = sigmoid.
template<int ACT>
__global__ __launch_bounds__(256) void k_aggregate(
    const int* __restrict__ row_ofs, const int* __restrict__ csr_src,
    const float* __restrict__ msg, const float* __restrict__ bias,
    float* __restrict__ out, int n) {
    const int node = blockIdx.x * 4 + (threadIdx.x >> 6);
    if (node >= n) return;
    const int lane = threadIdx.x & 63;
    const int beg = row_ofs[node];
    const int end = row_ofs[node + 1];
    float acc = 0.f;
    int j = beg;
    // 2-deep manual pipeline on the index load to break the dependent-load chain.
    for (; j + 2 <= end; j += 2) {
        int s0 = csr_src[j];
        int s1 = csr_src[j + 1];
        float v0 = msg[(size_t)s0 * FOUT + lane];
        float v1 = msg[(size_t)s1 * FOUT + lane];
        acc += v0 + v1;
    }
    if (j < end) {
        int s0 = csr_src[j];
        acc += msg[(size_t)s0 * FOUT + lane];
    }
    float v = acc + bias[lane];
    out[(size_t)node * FOUT + lane] =
        (ACT == 0) ? fmaxf(v, 0.f) : 1.f / (1.f + __expf(-v));
}

extern "C" void kernel_launch(void* const* d_in, const int* in_sizes, int n_in,
                              void* d_out, int out_size, void* d_ws, size_t ws_size,
                              hipStream_t stream) {
    const float* x  = (const float*)d_in[0];
    const int*   ei = (const int*)d_in[1];
    const float* W1 = (const float*)d_in[2];
    const float* b1 = (const float*)d_in[3];
    const float* W2 = (const float*)d_in[4];
    const float* b2 = (const float*)d_in[5];
    const float* W3 = (const float*)d_in[6];
    const float* b3 = (const float*)d_in[7];
    float* out = (float*)d_out;

    const int n  = in_sizes[0] / 128;   // 100000
    const int ne = in_sizes[1] / 2;     // 1600000
    const int* src = ei;
    const int* dst = ei + ne;

    const size_t feat_elems = (size_t)n * FOUT;

    // workspace layout
    float* A        = (float*)d_ws;                 // n*64 f32
    float* B        = A + feat_elems;               // n*64 f32
    int*   cnt      = (int*)(B + feat_elems);       // n
    int*   row_ofs  = cnt + n;                      // n+1
    int*   cursor   = row_ofs + n + 1;              // n
    int*   partials = cursor + n;                   // 128
    int*   partial_ofs = partials + 128;            // 128
    int*   csr_src  = partial_ofs + 128;            // ne

    const int nScanBlocks = (n + SCAN_ELEMS - 1) / SCAN_ELEMS;   // 98
    const int gAgg = (n + 3) / 4;                                 // 4 nodes/block

    // ---- CSR build (every call: ws is re-poisoned) ----
    hipMemsetAsync(cnt, 0, (size_t)n * sizeof(int), stream);
    k_hist<<<2048, 256, 0, stream>>>(dst, cnt, ne);
    k_scan1<<<nScanBlocks, SCAN_T, 0, stream>>>(cnt, row_ofs, partials, n);
    k_scan2<<<1, SCAN_T, 0, stream>>>(partials, partial_ofs, nScanBlocks);
    k_scan3<<<(n + 255) / 256, 256, 0, stream>>>(row_ofs, partial_ofs, cursor, n, ne);
    k_fill<<<2048, 256, 0, stream>>>(src, dst, cursor, csr_src, ne);

    // ---- Layer 1 ----
    k_linear<128><<<2048, 256, 0, stream>>>(x, W1, A, n);
    k_aggregate<0><<<gAgg, 256, 0, stream>>>(row_ofs, csr_src, A, b1, B, n);
    // ---- Layer 2 ----
    k_linear<64><<<2048, 256, 0, stream>>>(B, W2, A, n);
    k_aggregate<0><<<gAgg, 256, 0, stream>>>(row_ofs, csr_src, A, b2, B, n);
    // ---- Layer 3 ----
    k_linear<64><<<2048, 256, 0, stream>>>(B, W3, A, n);
    k_aggregate<1><<<gAgg, 256, 0, stream>>>(row_ofs, csr_src, A, b3, out, n);
}

// Round 5
// 593.423 us; speedup vs baseline: 7.4995x; 1.3175x over previous
//
#include <hip/hip_runtime.h>

// GCN: 3x (linear -> aggregate_by_dst(CSR) -> bias+act), atomic-free float path.
// N=100000, E=1600000, IN=128, HID=OUT=64.

#define FOUT 64
#define SCAN_T 256
#define SCAN_ELEMS 1024   // elements per scan block (4 per thread)

// ---------------- dense linear ----------------
// Register-tiled: block = 256 thr = 4 waves, 64 rows/block, full K staged.
// Thread owns 4 features x 4 rows; W and x both read as ds_read_b128.
// LDS cy/FMA ~1.5 vs 5.8 for the naive per-element version (m134 constants).
template<int K>
__global__ __launch_bounds__(256) void k_linear(
    const float* __restrict__ in, const float* __restrict__ W,
    float* __restrict__ out, int n) {
    constexpr int XSTR = (K == 128) ? 132 : 68;   // pad: row shift 4 banks, slots 2-way (free)
    __shared__ float4 sW4[K * 16];                // W[k][0..63] as 16 float4 per k
    __shared__ float xs[64 * XSTR];

    const int t = threadIdx.x;
    const int base = blockIdx.x * 64;

    // stage W (coalesced float4)
    const float4* W4 = (const float4*)W;
#pragma unroll
    for (int i = 0; i < K * 16 / 256; ++i) sW4[t + i * 256] = W4[t + i * 256];

    // stage x tile (coalesced float4, padded LDS rows)
    constexpr int CPR = K / 4;                    // float4 per row
#pragma unroll
    for (int i = 0; i < 64 * CPR / 256; ++i) {
        int flat = t + i * 256;
        int row = flat / CPR;
        int c4 = flat % CPR;
        int rg = base + row;
        if (rg < n) {
            float4 v = *(const float4*)(in + (size_t)rg * K + c4 * 4);
            *(float4*)&xs[row * XSTR + c4 * 4] = v;
        }
    }
    __syncthreads();

    const int fq = t & 15;            // feature quad (features 4fq..4fq+3)
    const int slot = (t >> 4) & 3;    // row slot within wave
    const int wave = t >> 6;
    const int r0 = wave * 16 + slot * 4;

    float4 acc[4];
#pragma unroll
    for (int i = 0; i < 4; ++i) acc[i] = make_float4(0.f, 0.f, 0.f, 0.f);

#pragma unroll 8
    for (int k = 0; k < K; k += 4) {
        float4 w0 = sW4[(k + 0) * 16 + fq];
        float4 w1 = sW4[(k + 1) * 16 + fq];
        float4 w2 = sW4[(k + 2) * 16 + fq];
        float4 w3 = sW4[(k + 3) * 16 + fq];
#pragma unroll
        for (int i = 0; i < 4; ++i) {
            float4 xv = *(const float4*)&xs[(r0 + i) * XSTR + k];
            acc[i].x = fmaf(xv.x, w0.x, acc[i].x);
            acc[i].y = fmaf(xv.x, w0.y, acc[i].y);
            acc[i].z = fmaf(xv.x, w0.z, acc[i].z);
            acc[i].w = fmaf(xv.x, w0.w, acc[i].w);
            acc[i].x = fmaf(xv.y, w1.x, acc[i].x);
            acc[i].y = fmaf(xv.y, w1.y, acc[i].y);
            acc[i].z = fmaf(xv.y, w1.z, acc[i].z);
            acc[i].w = fmaf(xv.y, w1.w, acc[i].w);
            acc[i].x = fmaf(xv.z, w2.x, acc[i].x);
            acc[i].y = fmaf(xv.z, w2.y, acc[i].y);
            acc[i].z = fmaf(xv.z, w2.z, acc[i].z);
            acc[i].w = fmaf(xv.z, w2.w, acc[i].w);
            acc[i].x = fmaf(xv.w, w3.x, acc[i].x);
            acc[i].y = fmaf(xv.w, w3.y, acc[i].y);
            acc[i].z = fmaf(xv.w, w3.z, acc[i].z);
            acc[i].w = fmaf(xv.w, w3.w, acc[i].w);
        }
    }

#pragma unroll
    for (int i = 0; i < 4; ++i) {
        int rg = base + r0 + i;
        if (rg < n) *(float4*)(out + (size_t)rg * FOUT + fq * 4) = acc[i];
    }
}

// ---------------- CSR build ----------------
__global__ __launch_bounds__(256) void k_hist(
    const int* __restrict__ dst, int* __restrict__ cnt, int ne) {
    const int stride = gridDim.x * blockDim.x;
    for (int i = blockIdx.x * blockDim.x + threadIdx.x; i < ne; i += stride)
        atomicAdd(&cnt[dst[i]], 1);
}

__global__ __launch_bounds__(SCAN_T) void k_scan1(
    const int* __restrict__ cnt, int* __restrict__ ex,
    int* __restrict__ partials, int n) {
    __shared__ int s[SCAN_T];
    const int base = blockIdx.x * SCAN_ELEMS;
    int vals[4];
    int sum = 0;
#pragma unroll
    for (int j = 0; j < 4; ++j) {
        int idx = base + threadIdx.x * 4 + j;
        int v = (idx < n) ? cnt[idx] : 0;
        vals[j] = sum;
        sum += v;
    }
    s[threadIdx.x] = sum;
    __syncthreads();
    for (int ofs = 1; ofs < SCAN_T; ofs <<= 1) {
        int v = (threadIdx.x >= ofs) ? s[threadIdx.x - ofs] : 0;
        __syncthreads();
        s[threadIdx.x] += v;
        __syncthreads();
    }
    const int texc = s[threadIdx.x] - sum;
#pragma unroll
    for (int j = 0; j < 4; ++j) {
        int idx = base + threadIdx.x * 4 + j;
        if (idx < n) ex[idx] = texc + vals[j];
    }
    if (threadIdx.x == SCAN_T - 1) partials[blockIdx.x] = s[threadIdx.x];
}

__global__ __launch_bounds__(SCAN_T) void k_scan2(
    const int* __restrict__ partials, int* __restrict__ partial_ofs, int nb) {
    __shared__ int s[SCAN_T];
    int v = (threadIdx.x < nb) ? partials[threadIdx.x] : 0;
    s[threadIdx.x] = v;
    __syncthreads();
    for (int ofs = 1; ofs < SCAN_T; ofs <<= 1) {
        int t = (threadIdx.x >= ofs) ? s[threadIdx.x - ofs] : 0;
        __syncthreads();
        s[threadIdx.x] += t;
        __syncthreads();
    }
    if (threadIdx.x < nb) partial_ofs[threadIdx.x] = s[threadIdx.x] - v;
}

__global__ __launch_bounds__(256) void k_scan3(
    int* __restrict__ row_ofs, const int* __restrict__ partial_ofs,
    int* __restrict__ cursor, int n, int ne) {
    const int i = blockIdx.x * blockDim.x + threadIdx.x;
    if (i < n) {
        int v = row_ofs[i] + partial_ofs[i >> 10];
        row_ofs[i] = v;
        cursor[i] = v;
    }
    if (i == 0) row_ofs[n] = ne;
}

__global__ __launch_bounds__(256) void k_fill(
    const int* __restrict__ src, const int* __restrict__ dst,
    int* __restrict__ cursor, int* __restrict__ csr_src, int ne) {
    const int stride = gridDim.x * blockDim.x;
    for (int i = blockIdx.x * blockDim.x + threadIdx.x; i < ne; i += stride) {
        int d = dst[i];
        int p = atomicAdd(&cursor[d], 1);
        csr_src[p] = src[i];
    }
}

// ---------------- aggregation (gather-reduce) ----------------
// One wave per node; lane = feature. 4-deep load pipeline on the random
// gathers (avg degree 16). Bias + activation fused. ACT: 0 = ReLU, 1 = sigmoid.
template<int ACT>
__global__ __launch_bounds__(256) void k_aggregate(
    const int* __restrict__ row_ofs, const int* __restrict__ csr_src,
    const float* __restrict__ msg, const float* __restrict__ bias,
    float* __restrict__ out, int n) {
    const int node = blockIdx.x * 4 + (threadIdx.x >> 6);
    if (node >= n) return;
    const int lane = threadIdx.x & 63;
    const int beg = row_ofs[node];
    const int end = row_ofs[node + 1];
    float acc = 0.f;
    int j = beg;
    for (; j + 4 <= end; j += 4) {
        int s0 = csr_src[j];
        int s1 = csr_src[j + 1];
        int s2 = csr_src[j + 2];
        int s3 = csr_src[j + 3];
        float v0 = msg[(size_t)s0 * FOUT + lane];
        float v1 = msg[(size_t)s1 * FOUT + lane];
        float v2 = msg[(size_t)s2 * FOUT + lane];
        float v3 = msg[(size_t)s3 * FOUT + lane];
        acc += (v0 + v1) + (v2 + v3);
    }
    for (; j < end; ++j)
        acc += msg[(size_t)csr_src[j] * FOUT + lane];
    float v = acc + bias[lane];
    out[(size_t)node * FOUT + lane] =
        (ACT == 0) ? fmaxf(v, 0.f) : 1.f / (1.f + __expf(-v));
}

extern "C" void kernel_launch(void* const* d_in, const int* in_sizes, int n_in,
                              void* d_out, int out_size, void* d_ws, size_t ws_size,
                              hipStream_t stream) {
    const float* x  = (const float*)d_in[0];
    const int*   ei = (const int*)d_in[1];
    const float* W1 = (const float*)d_in[2];
    const float* b1 = (const float*)d_in[3];
    const float* W2 = (const float*)d_in[4];
    const float* b2 = (const float*)d_in[5];
    const float* W3 = (const float*)d_in[6];
    const float* b3 = (const float*)d_in[7];
    float* out = (float*)d_out;

    const int n  = in_sizes[0] / 128;   // 100000
    const int ne = in_sizes[1] / 2;     // 1600000
    const int* src = ei;
    const int* dst = ei + ne;

    const size_t feat_elems = (size_t)n * FOUT;

    // workspace layout
    float* A        = (float*)d_ws;                 // n*64 f32
    float* B        = A + feat_elems;               // n*64 f32
    int*   cnt      = (int*)(B + feat_elems);       // n
    int*   row_ofs  = cnt + n;                      // n+1
    int*   cursor   = row_ofs + n + 1;              // n
    int*   partials = cursor + n;                   // 128
    int*   partial_ofs = partials + 128;            // 128
    int*   csr_src  = partial_ofs + 128;            // ne

    const int nScanBlocks = (n + SCAN_ELEMS - 1) / SCAN_ELEMS;   // 98
    const int gAgg = (n + 3) / 4;
    const int gLin = (n + 63) / 64;

    // ---- CSR build (every call: ws is re-poisoned) ----
    hipMemsetAsync(cnt, 0, (size_t)n * sizeof(int), stream);
    k_hist<<<2048, 256, 0, stream>>>(dst, cnt, ne);
    k_scan1<<<nScanBlocks, SCAN_T, 0, stream>>>(cnt, row_ofs, partials, n);
    k_scan2<<<1, SCAN_T, 0, stream>>>(partials, partial_ofs, nScanBlocks);
    k_scan3<<<(n + 255) / 256, 256, 0, stream>>>(row_ofs, partial_ofs, cursor, n, ne);
    k_fill<<<2048, 256, 0, stream>>>(src, dst, cursor, csr_src, ne);

    // ---- Layer 1 ----
    k_linear<128><<<gLin, 256, 0, stream>>>(x, W1, A, n);
    k_aggregate<0><<<gAgg, 256, 0, stream>>>(row_ofs, csr_src, A, b1, B, n);
    // ---- Layer 2 ----
    k_linear<64><<<gLin, 256, 0, stream>>>(B, W2, A, n);
    k_aggregate<0><<<gAgg, 256, 0, stream>>>(row_ofs, csr_src, A, b2, B, n);
    // ---- Layer 3 ----
    k_linear<64><<<gLin, 256, 0, stream>>>(B, W3, A, n);
    k_aggregate<1><<<gAgg, 256, 0, stream>>>(row_ofs, csr_src, A, b3, out, n);
}